// Round 3
// baseline (498.768 us; speedup 1.0000x reference)
//
#include <hip/hip_runtime.h>

#define B_ 8
#define N_ 4096
#define F_ 512

// S (512 x 64) = [left | right | left_local | right_local], each [512][16] row-major.
__device__ __forceinline__ float Sval(const float* l, const float* r,
                                      const float* ll, const float* rl,
                                      int h, int e) {
    const int m = e >> 4, c = e & 15;
    const float* p = (m == 0) ? l : (m == 1) ? r : (m == 2) ? ll : rl;
    return p[h * 16 + c];
}

__device__ __forceinline__ float qval(const float* coeff, const float* coeff_l,
                                      int b, int j) {
    if (j < 16) return 1.f;
    if (j < 32) return coeff[b * 16 + (j - 16)];
    if (j < 48) return 1.f;
    return coeff_l[b * 16 + (j - 48)];
}

__device__ __forceinline__ float lane_bcast(float v, int lane) {
    return __int_as_float(__builtin_amdgcn_readlane(__float_as_int(v), lane));
}

// GS = S^T S  (64x64). One block per row i.
__global__ __launch_bounds__(256) void k_gram(const float* l, const float* r,
                                              const float* ll, const float* rl,
                                              float* GS) {
    __shared__ float red[4][64];
    const int i = blockIdx.x;
    const int t = threadIdx.x;
    const int j = t & 63, seg = t >> 6;
    float acc = 0.f;
    const int h0 = seg * 128;
    for (int h = h0; h < h0 + 128; ++h)
        acc += Sval(l, r, ll, rl, h, i) * Sval(l, r, ll, rl, h, j);
    red[seg][j] = acc;
    __syncthreads();
    if (t < 64) GS[i * 64 + t] = red[0][t] + red[1][t] + red[2][t] + red[3][t];
}

// Build CP (64x64) and M = I - 0.5 CQ^T GS CP -> Mws, CPws. 8 blocks.
__global__ __launch_bounds__(256) void k_build_pre(const float* coeff, const float* gate,
                                                   const float* coeff_l, const float* gate_l,
                                                   const float* comm, const float* GS,
                                                   float* Mws, float* CPws) {
    __shared__ float GST[4096];
    __shared__ float CPs[4096];
    __shared__ float ABs[2048];
    __shared__ float u1s[32], u2s[32];

    const int b = blockIdx.x, t = threadIdx.x;
    const int tx = t & 15, ty = t >> 4;
    const float g = gate[b], gl = gate_l[b];
    const float cs = comm[b] / 12.0f;

    // (a) u1/u2 + GST[e*64+i] = -0.5*q(i)*GS[(i^16)][e]
    if (t < 32) {
        u1s[t] = (t < 16) ? g * coeff[b * 16 + t] : -g;
        u2s[t] = (t < 16) ? gl * coeff_l[b * 16 + t] : -gl;
    }
    for (int idx = t; idx < 4096; idx += 256) {
        const int i = idx & 63, e = idx >> 6;
        GST[idx] = -0.5f * qval(coeff, coeff_l, b, i) * GS[(i ^ 16) * 64 + e];
    }
    __syncthreads();

    // (b) AB: A [32][32] at 0, B at 1024
    for (int idx = t; idx < 2048; idx += 256) {
        const int which = idx >> 10;
        const int i = (idx >> 5) & 31, j = idx & 31;
        float val;
        if (which == 0) {
            const int v2i = (i < 16) ? 48 + i : 16 + i;
            const float v2sc = (i < 16) ? 1.f : coeff_l[b * 16 + (i - 16)];
            val = v2sc * u1s[j] * GS[v2i * 64 + j];
        } else {
            const int v1i = (i < 16) ? 16 + i : i - 16;
            const float v1sc = (i < 16) ? 1.f : coeff[b * 16 + (i - 16)];
            val = v1sc * u2s[j] * GS[v1i * 64 + 32 + j];
        }
        ABs[idx] = val;
    }
    __syncthreads();

    // (c) CP -> LDS + global
    for (int idx = t; idx < 4096; idx += 256) {
        const int e = idx >> 6, j = idx & 63;
        float val = 0.f;
        if (j < 32) {
            if (e == j) val += 0.5f * u1s[j];
            if (e >= 32) val += cs * u2s[e - 32] * ABs[(e - 32) * 32 + j];
        } else {
            const int jp = j - 32;
            if (e == 32 + jp) val += 0.5f * u2s[jp];
            if (e < 32) val -= cs * u1s[e] * ABs[1024 + e * 32 + jp];
        }
        CPs[idx] = val;
        CPws[b * 4096 + idx] = val;
    }
    __syncthreads();

    // (d) M[i][m] = d(i,m) + sum_e GST[e][i] * CP[e][m]  (4x4 register tile) -> Mws
    {
        const int i0 = ty * 4, m0 = tx * 4;
        float acc[4][4];
#pragma unroll
        for (int i = 0; i < 4; ++i)
#pragma unroll
            for (int j = 0; j < 4; ++j) acc[i][j] = 0.f;
        for (int e = 0; e < 64; ++e) {
            const float4 av = *reinterpret_cast<const float4*>(&GST[e * 64 + i0]);
            const float4 bv = *reinterpret_cast<const float4*>(&CPs[e * 64 + m0]);
            const float a[4] = {av.x, av.y, av.z, av.w};
            const float bb[4] = {bv.x, bv.y, bv.z, bv.w};
#pragma unroll
            for (int i = 0; i < 4; ++i)
#pragma unroll
                for (int j = 0; j < 4; ++j) acc[i][j] += a[i] * bb[j];
        }
#pragma unroll
        for (int i = 0; i < 4; ++i) {
            float4 o;
            o.x = acc[i][0] + (((i0 + i) == (m0 + 0)) ? 1.f : 0.f);
            o.y = acc[i][1] + (((i0 + i) == (m0 + 1)) ? 1.f : 0.f);
            o.z = acc[i][2] + (((i0 + i) == (m0 + 2)) ? 1.f : 0.f);
            o.w = acc[i][3] + (((i0 + i) == (m0 + 3)) ? 1.f : 0.f);
            *reinterpret_cast<float4*>(&Mws[b * 4096 + (i0 + i) * 64 + m0]) = o;
        }
    }
}

// Single-wave register Gauss-Jordan (no pivoting), K = M^{-1}. 8 blocks x 64 thr.
// __launch_bounds__(64,1): full VGPR budget -> a[64] stays in registers, no spill.
__global__ __launch_bounds__(64, 1) void k_inv(const float* Mws, float* Kws) {
    const int b = blockIdx.x, t = threadIdx.x;  // lane t owns column t
    float a[64];
#pragma unroll
    for (int rr = 0; rr < 64; ++rr) a[rr] = Mws[b * 4096 + rr * 64 + t];
#pragma unroll
    for (int k = 0; k < 64; ++k) {
        const float dk = lane_bcast(a[k], k);
        const float inv = 1.0f / dk;
        a[k] = (t == k) ? inv : a[k] * inv;
#pragma unroll
        for (int rr = 0; rr < 64; ++rr) {
            if (rr == k) continue;
            const float f = lane_bcast(a[rr], k);
            const float v = (t == k) ? 0.f : a[rr];
            a[rr] = v - f * a[k];
        }
    }
#pragma unroll
    for (int rr = 0; rr < 64; ++rr) Kws[b * 4096 + rr * 64 + t] = a[rr];
}

// Newton refinement + E: Td = CP*K, Ta = M*K, T1 = Td*(2I-Ta) = 2Td - Td*Ta,
// E[e][f] = q(f^16) * T1[e][f^16]. 8 blocks.
__global__ __launch_bounds__(256) void k_build_post(const float* coeff, const float* coeff_l,
                                                    const float* Mws, const float* CPws,
                                                    const float* Kws, float* Eout) {
    __shared__ float Ms[4096], CPs[4096], Ks[4096], Tds[4096], Tas[4096];
    const int b = blockIdx.x, t = threadIdx.x;
    const int tx = t & 15, ty = t >> 4;

    for (int idx = t; idx < 4096; idx += 256) {
        Ms[idx] = Mws[b * 4096 + idx];
        CPs[idx] = CPws[b * 4096 + idx];
        Ks[idx] = Kws[b * 4096 + idx];
    }
    __syncthreads();

    // Td = CP*K ; Ta = M*K  (two 4x4 tiles per thread, shared B-column loads)
    {
        const int i0 = ty * 4, j0 = tx * 4;
        float accd[4][4], acca[4][4];
#pragma unroll
        for (int i = 0; i < 4; ++i)
#pragma unroll
            for (int j = 0; j < 4; ++j) { accd[i][j] = 0.f; acca[i][j] = 0.f; }
        for (int q = 0; q < 64; ++q) {
            const float4 bv = *reinterpret_cast<const float4*>(&Ks[q * 64 + j0]);
            const float bb[4] = {bv.x, bv.y, bv.z, bv.w};
            float ad[4], aa[4];
#pragma unroll
            for (int i = 0; i < 4; ++i) {
                ad[i] = CPs[(i0 + i) * 64 + q];
                aa[i] = Ms[(i0 + i) * 64 + q];
            }
#pragma unroll
            for (int i = 0; i < 4; ++i)
#pragma unroll
                for (int j = 0; j < 4; ++j) {
                    accd[i][j] += ad[i] * bb[j];
                    acca[i][j] += aa[i] * bb[j];
                }
        }
#pragma unroll
        for (int i = 0; i < 4; ++i)
#pragma unroll
            for (int j = 0; j < 4; ++j) {
                Tds[(i0 + i) * 64 + j0 + j] = accd[i][j];
                Tas[(i0 + i) * 64 + j0 + j] = acca[i][j];
            }
    }
    __syncthreads();

    // T1 = 2*Td - Td*Ta ; E[e][(c0^16)+j] = q(c0+j) * T1[e][c0+j]
    {
        const int e0 = ty * 4, c0 = tx * 4;
        float acc[4][4];
#pragma unroll
        for (int i = 0; i < 4; ++i)
#pragma unroll
            for (int j = 0; j < 4; ++j) acc[i][j] = 0.f;
        for (int q = 0; q < 64; ++q) {
            const float4 bv = *reinterpret_cast<const float4*>(&Tas[q * 64 + c0]);
            const float bb[4] = {bv.x, bv.y, bv.z, bv.w};
            float a[4];
#pragma unroll
            for (int i = 0; i < 4; ++i) a[i] = Tds[(e0 + i) * 64 + q];
#pragma unroll
            for (int i = 0; i < 4; ++i)
#pragma unroll
                for (int j = 0; j < 4; ++j) acc[i][j] += a[i] * bb[j];
        }
        float qv[4];
#pragma unroll
        for (int j = 0; j < 4; ++j) qv[j] = qval(coeff, coeff_l, b, c0 + j);
#pragma unroll
        for (int i = 0; i < 4; ++i) {
            float4 o;
            o.x = qv[0] * (2.f * Tds[(e0 + i) * 64 + c0 + 0] - acc[i][0]);
            o.y = qv[1] * (2.f * Tds[(e0 + i) * 64 + c0 + 1] - acc[i][1]);
            o.z = qv[2] * (2.f * Tds[(e0 + i) * 64 + c0 + 2] - acc[i][2]);
            o.w = qv[3] * (2.f * Tds[(e0 + i) * 64 + c0 + 3] - acc[i][3]);
            *reinterpret_cast<float4*>(&Eout[b * 4096 + (e0 + i) * 64 + (c0 ^ 16)]) = o;
        }
    }
}

// SE_b = S * E_b   (512 x 64). grid (hc=8, b=8)
__global__ __launch_bounds__(256) void k_se(const float* l, const float* r,
                                            const float* ll, const float* rl,
                                            const float* Ein, float* SEout) {
    __shared__ float Es[4096];
    const int b = blockIdx.y, hc = blockIdx.x, t = threadIdx.x;
    for (int idx = t; idx < 4096; idx += 256) Es[idx] = Ein[b * 4096 + idx];
    __syncthreads();
    const int h = hc * 64 + (t >> 2);
    const int mg = (t & 3) * 16;
    float acc[16];
#pragma unroll
    for (int q = 0; q < 16; ++q) acc[q] = 0.f;
#pragma unroll 4
    for (int e = 0; e < 64; ++e) {
        const float s = Sval(l, r, ll, rl, h, e);
        const float* Er = Es + e * 64 + mg;
#pragma unroll
        for (int q = 0; q < 16; ++q) acc[q] += s * Er[q];
    }
    float* o = SEout + (size_t)b * (512 * 64) + h * 64 + mg;
#pragma unroll
    for (int q = 0; q < 4; ++q) {
        float4 v;
        v.x = acc[q * 4 + 0]; v.y = acc[q * 4 + 1];
        v.z = acc[q * 4 + 2]; v.w = acc[q * 4 + 3];
        *reinterpret_cast<float4*>(o + q * 4) = v;
    }
}

// out = x + ((x * SE_b) * S^T).  grid (row-tile=64, b=8), 64 rows per block.
__global__ __launch_bounds__(256) void k_mix(const float* x, const float* l, const float* r,
                                             const float* ll, const float* rl,
                                             const float* SE, float* out) {
    __shared__ float smem[12800];
    float* XsT = smem;
    float* SEs = smem + 4352;
    float* ZsT = smem;
    float* SsT = smem + 4352;

    const int b = blockIdx.y;
    const int r0 = blockIdx.x * 64;
    const int t = threadIdx.x;
    const int tx = t & 15, ty = t >> 4;
    const float* xb = x + (size_t)b * N_ * F_;
    float* outb = out + (size_t)b * N_ * F_;
    const float* SEb = SE + (size_t)b * (512 * 64);

    float acc[4][4];
#pragma unroll
    for (int i = 0; i < 4; ++i)
#pragma unroll
        for (int j = 0; j < 4; ++j) acc[i][j] = 0.f;

    const int lr = t >> 2;
    const int lc = (t & 3) * 16;

    // phase 1: Z[64][64] = X_tile[64][512] * SE[512][64]
    for (int kc = 0; kc < 8; ++kc) {
#pragma unroll
        for (int i = 0; i < 4; ++i) {
            const float4 v = *reinterpret_cast<const float4*>(
                xb + (size_t)(r0 + lr) * F_ + kc * 64 + lc + i * 4);
            XsT[(lc + i * 4 + 0) * 68 + lr] = v.x;
            XsT[(lc + i * 4 + 1) * 68 + lr] = v.y;
            XsT[(lc + i * 4 + 2) * 68 + lr] = v.z;
            XsT[(lc + i * 4 + 3) * 68 + lr] = v.w;
            const float4 w = *reinterpret_cast<const float4*>(
                SEb + (size_t)(kc * 64 + lr) * 64 + lc + i * 4);
            *reinterpret_cast<float4*>(&SEs[lr * 68 + lc + i * 4]) = w;
        }
        __syncthreads();
#pragma unroll 8
        for (int k = 0; k < 64; ++k) {
            const float4 a4 = *reinterpret_cast<const float4*>(&XsT[k * 68 + 4 * ty]);
            const float4 b4 = *reinterpret_cast<const float4*>(&SEs[k * 68 + 4 * tx]);
            const float av[4] = {a4.x, a4.y, a4.z, a4.w};
            const float bv[4] = {b4.x, b4.y, b4.z, b4.w};
#pragma unroll
            for (int i = 0; i < 4; ++i)
#pragma unroll
                for (int j = 0; j < 4; ++j) acc[i][j] += av[i] * bv[j];
        }
        __syncthreads();
    }

    // ZsT[m][r] = z[r][m]
#pragma unroll
    for (int j = 0; j < 4; ++j)
#pragma unroll
        for (int i = 0; i < 4; ++i)
            ZsT[(4 * tx + j) * 68 + 4 * ty + i] = acc[i][j];
    __syncthreads();

    // phase 2: out[64][512] = X + Z * S^T, h-chunks of 128
    for (int hc = 0; hc < 4; ++hc) {
        {
            const int gsel = t & 3;
            const int hl = t >> 2;
            const float* mat = (gsel == 0) ? l : (gsel == 1) ? r : (gsel == 2) ? ll : rl;
#pragma unroll
            for (int hh = 0; hh < 2; ++hh) {
                const int hloc = hl + hh * 64;
                const int h = hc * 128 + hloc;
#pragma unroll
                for (int q = 0; q < 4; ++q) {
                    const float4 v = *reinterpret_cast<const float4*>(mat + h * 16 + q * 4);
                    SsT[(gsel * 16 + q * 4 + 0) * 132 + hloc] = v.x;
                    SsT[(gsel * 16 + q * 4 + 1) * 132 + hloc] = v.y;
                    SsT[(gsel * 16 + q * 4 + 2) * 132 + hloc] = v.z;
                    SsT[(gsel * 16 + q * 4 + 3) * 132 + hloc] = v.w;
                }
            }
        }
        __syncthreads();

        float oacc[4][8];
#pragma unroll
        for (int i = 0; i < 4; ++i)
#pragma unroll
            for (int j = 0; j < 8; ++j) oacc[i][j] = 0.f;

#pragma unroll 8
        for (int e = 0; e < 64; ++e) {
            const float4 z4 = *reinterpret_cast<const float4*>(&ZsT[e * 68 + 4 * ty]);
            const float4 s0 = *reinterpret_cast<const float4*>(&SsT[e * 132 + 8 * tx]);
            const float4 s1 = *reinterpret_cast<const float4*>(&SsT[e * 132 + 8 * tx + 4]);
            const float zv[4] = {z4.x, z4.y, z4.z, z4.w};
            const float sv[8] = {s0.x, s0.y, s0.z, s0.w, s1.x, s1.y, s1.z, s1.w};
#pragma unroll
            for (int i = 0; i < 4; ++i)
#pragma unroll
                for (int j = 0; j < 8; ++j) oacc[i][j] += zv[i] * sv[j];
        }

#pragma unroll
        for (int i = 0; i < 4; ++i) {
            const size_t row = (size_t)(r0 + 4 * ty + i);
            const float* xr = xb + row * F_ + hc * 128 + 8 * tx;
            float* orow = outb + row * F_ + hc * 128 + 8 * tx;
            const float4 x0 = *reinterpret_cast<const float4*>(xr);
            const float4 x1 = *reinterpret_cast<const float4*>(xr + 4);
            float4 o0, o1;
            o0.x = x0.x + oacc[i][0]; o0.y = x0.y + oacc[i][1];
            o0.z = x0.z + oacc[i][2]; o0.w = x0.w + oacc[i][3];
            o1.x = x1.x + oacc[i][4]; o1.y = x1.y + oacc[i][5];
            o1.z = x1.z + oacc[i][6]; o1.w = x1.w + oacc[i][7];
            *reinterpret_cast<float4*>(orow) = o0;
            *reinterpret_cast<float4*>(orow + 4) = o1;
        }
        __syncthreads();
    }
}

extern "C" void kernel_launch(void* const* d_in, const int* in_sizes, int n_in,
                              void* d_out, int out_size, void* d_ws, size_t ws_size,
                              hipStream_t stream) {
    (void)in_sizes; (void)n_in; (void)out_size; (void)ws_size;
    const float* x       = (const float*)d_in[0];
    const float* coeff   = (const float*)d_in[1];
    const float* gate    = (const float*)d_in[2];
    const float* coeff_l = (const float*)d_in[3];
    const float* gate_l  = (const float*)d_in[4];
    const float* comm    = (const float*)d_in[5];
    const float* l       = (const float*)d_in[6];
    const float* r       = (const float*)d_in[7];
    const float* ll      = (const float*)d_in[8];
    const float* rl      = (const float*)d_in[9];

    float* wsf = (float*)d_ws;
    float* GS  = wsf;                        // 4096
    float* E   = wsf + 4096;                 // 8 * 4096
    float* SE  = wsf + 4096 + 8 * 4096;      // 8 * 512 * 64 = 262144
    float* Mws = SE + 262144;                // 8 * 4096
    float* CPws = Mws + 8 * 4096;            // 8 * 4096
    float* Kws  = CPws + 8 * 4096;           // 8 * 4096
    float* out = (float*)d_out;

    k_gram<<<dim3(64), dim3(256), 0, stream>>>(l, r, ll, rl, GS);
    k_build_pre<<<dim3(8), dim3(256), 0, stream>>>(coeff, gate, coeff_l, gate_l, comm, GS,
                                                   Mws, CPws);
    k_inv<<<dim3(8), dim3(64), 0, stream>>>(Mws, Kws);
    k_build_post<<<dim3(8), dim3(256), 0, stream>>>(coeff, coeff_l, Mws, CPws, Kws, E);
    k_se<<<dim3(8, 8), dim3(256), 0, stream>>>(l, r, ll, rl, E, SE);
    k_mix<<<dim3(64, 8), dim3(256), 0, stream>>>(x, l, r, ll, rl, SE, out);
}

// Round 4
// 160.805 us; speedup vs baseline: 3.1017x; 3.1017x over previous
//
#include <hip/hip_runtime.h>

#define B_ 8
#define N_ 4096
#define F_ 512

// S (512 x 64) = [left | right | left_local | right_local], each [512][16] row-major.
__device__ __forceinline__ float Sval(const float* l, const float* r,
                                      const float* ll, const float* rl,
                                      int h, int e) {
    const int m = e >> 4, c = e & 15;
    const float* p = (m == 0) ? l : (m == 1) ? r : (m == 2) ? ll : rl;
    return p[h * 16 + c];
}

__device__ __forceinline__ float qval(const float* coeff, const float* coeff_l,
                                      int b, int j) {
    if (j < 16) return 1.f;
    if (j < 32) return coeff[b * 16 + (j - 16)];
    if (j < 48) return 1.f;
    return coeff_l[b * 16 + (j - 48)];
}

__device__ __forceinline__ float lane_bcast(float v, int lane) {
    return __int_as_float(__builtin_amdgcn_readlane(__float_as_int(v), lane));
}

// GS = S^T S  (64x64). One block per row i.
__global__ __launch_bounds__(256) void k_gram(const float* l, const float* r,
                                              const float* ll, const float* rl,
                                              float* GS) {
    __shared__ float red[4][64];
    const int i = blockIdx.x;
    const int t = threadIdx.x;
    const int j = t & 63, seg = t >> 6;
    float acc = 0.f;
    const int h0 = seg * 128;
    for (int h = h0; h < h0 + 128; ++h)
        acc += Sval(l, r, ll, rl, h, i) * Sval(l, r, ll, rl, h, j);
    red[seg][j] = acc;
    __syncthreads();
    if (t < 64) GS[i * 64 + t] = red[0][t] + red[1][t] + red[2][t] + red[3][t];
}

// Build CP (64x64) and M = I - 0.5 CQ^T GS CP -> Mws, CPws. 8 blocks.
__global__ __launch_bounds__(256) void k_build_pre(const float* coeff, const float* gate,
                                                   const float* coeff_l, const float* gate_l,
                                                   const float* comm, const float* GS,
                                                   float* Mws, float* CPws) {
    __shared__ float GST[4096];
    __shared__ float CPs[4096];
    __shared__ float ABs[2048];
    __shared__ float u1s[32], u2s[32];

    const int b = blockIdx.x, t = threadIdx.x;
    const int tx = t & 15, ty = t >> 4;
    const float g = gate[b], gl = gate_l[b];
    const float cs = comm[b] / 12.0f;

    // (a) u1/u2 + GST[e*64+i] = -0.5*q(i)*GS[(i^16)][e]
    if (t < 32) {
        u1s[t] = (t < 16) ? g * coeff[b * 16 + t] : -g;
        u2s[t] = (t < 16) ? gl * coeff_l[b * 16 + t] : -gl;
    }
    for (int idx = t; idx < 4096; idx += 256) {
        const int i = idx & 63, e = idx >> 6;
        GST[idx] = -0.5f * qval(coeff, coeff_l, b, i) * GS[(i ^ 16) * 64 + e];
    }
    __syncthreads();

    // (b) AB: A [32][32] at 0, B at 1024
    for (int idx = t; idx < 2048; idx += 256) {
        const int which = idx >> 10;
        const int i = (idx >> 5) & 31, j = idx & 31;
        float val;
        if (which == 0) {
            const int v2i = (i < 16) ? 48 + i : 16 + i;
            const float v2sc = (i < 16) ? 1.f : coeff_l[b * 16 + (i - 16)];
            val = v2sc * u1s[j] * GS[v2i * 64 + j];
        } else {
            const int v1i = (i < 16) ? 16 + i : i - 16;
            const float v1sc = (i < 16) ? 1.f : coeff[b * 16 + (i - 16)];
            val = v1sc * u2s[j] * GS[v1i * 64 + 32 + j];
        }
        ABs[idx] = val;
    }
    __syncthreads();

    // (c) CP -> LDS + global
    for (int idx = t; idx < 4096; idx += 256) {
        const int e = idx >> 6, j = idx & 63;
        float val = 0.f;
        if (j < 32) {
            if (e == j) val += 0.5f * u1s[j];
            if (e >= 32) val += cs * u2s[e - 32] * ABs[(e - 32) * 32 + j];
        } else {
            const int jp = j - 32;
            if (e == 32 + jp) val += 0.5f * u2s[jp];
            if (e < 32) val -= cs * u1s[e] * ABs[1024 + e * 32 + jp];
        }
        CPs[idx] = val;
        CPws[b * 4096 + idx] = val;
    }
    __syncthreads();

    // (d) M[i][m] = d(i,m) + sum_e GST[e][i] * CP[e][m]  (4x4 register tile) -> Mws
    {
        const int i0 = ty * 4, m0 = tx * 4;
        float acc[4][4];
#pragma unroll
        for (int i = 0; i < 4; ++i)
#pragma unroll
            for (int j = 0; j < 4; ++j) acc[i][j] = 0.f;
        for (int e = 0; e < 64; ++e) {
            const float4 av = *reinterpret_cast<const float4*>(&GST[e * 64 + i0]);
            const float4 bv = *reinterpret_cast<const float4*>(&CPs[e * 64 + m0]);
            const float a[4] = {av.x, av.y, av.z, av.w};
            const float bb[4] = {bv.x, bv.y, bv.z, bv.w};
#pragma unroll
            for (int i = 0; i < 4; ++i)
#pragma unroll
                for (int j = 0; j < 4; ++j) acc[i][j] += a[i] * bb[j];
        }
#pragma unroll
        for (int i = 0; i < 4; ++i) {
            float4 o;
            o.x = acc[i][0] + (((i0 + i) == (m0 + 0)) ? 1.f : 0.f);
            o.y = acc[i][1] + (((i0 + i) == (m0 + 1)) ? 1.f : 0.f);
            o.z = acc[i][2] + (((i0 + i) == (m0 + 2)) ? 1.f : 0.f);
            o.w = acc[i][3] + (((i0 + i) == (m0 + 3)) ? 1.f : 0.f);
            *reinterpret_cast<float4*>(&Mws[b * 4096 + (i0 + i) * 64 + m0]) = o;
        }
    }
}

// ---- k_inv: single-wave register Gauss-Jordan, macro-forced full unroll ----
// Every array index is a source-level LITERAL so SROA keeps a[64] in VGPRs
// (runtime-indexed local arrays get committed to scratch before the unroller
// runs — that was the 400us failure mode of the loop version).
#define DO64(M, K) \
    M(0, K) M(1, K) M(2, K) M(3, K) M(4, K) M(5, K) M(6, K) M(7, K) \
    M(8, K) M(9, K) M(10, K) M(11, K) M(12, K) M(13, K) M(14, K) M(15, K) \
    M(16, K) M(17, K) M(18, K) M(19, K) M(20, K) M(21, K) M(22, K) M(23, K) \
    M(24, K) M(25, K) M(26, K) M(27, K) M(28, K) M(29, K) M(30, K) M(31, K) \
    M(32, K) M(33, K) M(34, K) M(35, K) M(36, K) M(37, K) M(38, K) M(39, K) \
    M(40, K) M(41, K) M(42, K) M(43, K) M(44, K) M(45, K) M(46, K) M(47, K) \
    M(48, K) M(49, K) M(50, K) M(51, K) M(52, K) M(53, K) M(54, K) M(55, K) \
    M(56, K) M(57, K) M(58, K) M(59, K) M(60, K) M(61, K) M(62, K) M(63, K)

#define GJ_LOAD(RR, K) a[RR] = Mws[base + (RR)*64 + t];
#define GJ_STORE(RR, K) Kws[base + (RR)*64 + t] = a[RR];
#define GJ_UPD(RR, K) \
    if ((RR) != (K)) { \
        const float f = lane_bcast(a[RR], (K)); \
        a[RR] = ((t == (K)) ? 0.f : a[RR]) - f * a[K]; \
    }
#define GJ_STEP(K) { \
    const float dk = lane_bcast(a[K], (K)); \
    const float pinv = 1.0f / dk; \
    a[K] = (t == (K)) ? pinv : a[K] * pinv; \
    DO64(GJ_UPD, K) \
}

__global__ __launch_bounds__(64, 1) void k_inv(const float* Mws, float* Kws) {
    const int b = blockIdx.x, t = threadIdx.x;  // lane t owns column t
    const int base = b * 4096;
    float a[64];
    DO64(GJ_LOAD, 0)
    GJ_STEP(0) GJ_STEP(1) GJ_STEP(2) GJ_STEP(3)
    GJ_STEP(4) GJ_STEP(5) GJ_STEP(6) GJ_STEP(7)
    GJ_STEP(8) GJ_STEP(9) GJ_STEP(10) GJ_STEP(11)
    GJ_STEP(12) GJ_STEP(13) GJ_STEP(14) GJ_STEP(15)
    GJ_STEP(16) GJ_STEP(17) GJ_STEP(18) GJ_STEP(19)
    GJ_STEP(20) GJ_STEP(21) GJ_STEP(22) GJ_STEP(23)
    GJ_STEP(24) GJ_STEP(25) GJ_STEP(26) GJ_STEP(27)
    GJ_STEP(28) GJ_STEP(29) GJ_STEP(30) GJ_STEP(31)
    GJ_STEP(32) GJ_STEP(33) GJ_STEP(34) GJ_STEP(35)
    GJ_STEP(36) GJ_STEP(37) GJ_STEP(38) GJ_STEP(39)
    GJ_STEP(40) GJ_STEP(41) GJ_STEP(42) GJ_STEP(43)
    GJ_STEP(44) GJ_STEP(45) GJ_STEP(46) GJ_STEP(47)
    GJ_STEP(48) GJ_STEP(49) GJ_STEP(50) GJ_STEP(51)
    GJ_STEP(52) GJ_STEP(53) GJ_STEP(54) GJ_STEP(55)
    GJ_STEP(56) GJ_STEP(57) GJ_STEP(58) GJ_STEP(59)
    GJ_STEP(60) GJ_STEP(61) GJ_STEP(62) GJ_STEP(63)
    DO64(GJ_STORE, 0)
}

// Newton refinement + E: Td = CP*K, Ta = M*K, T1 = Td*(2I-Ta) = 2Td - Td*Ta,
// E[e][f] = q(f^16) * T1[e][f^16]. 8 blocks.
__global__ __launch_bounds__(256) void k_build_post(const float* coeff, const float* coeff_l,
                                                    const float* Mws, const float* CPws,
                                                    const float* Kws, float* Eout) {
    __shared__ float Ms[4096], CPs[4096], Ks[4096], Tds[4096], Tas[4096];
    const int b = blockIdx.x, t = threadIdx.x;
    const int tx = t & 15, ty = t >> 4;

    for (int idx = t; idx < 4096; idx += 256) {
        Ms[idx] = Mws[b * 4096 + idx];
        CPs[idx] = CPws[b * 4096 + idx];
        Ks[idx] = Kws[b * 4096 + idx];
    }
    __syncthreads();

    // Td = CP*K ; Ta = M*K  (two 4x4 tiles per thread, shared B-column loads)
    {
        const int i0 = ty * 4, j0 = tx * 4;
        float accd[4][4], acca[4][4];
#pragma unroll
        for (int i = 0; i < 4; ++i)
#pragma unroll
            for (int j = 0; j < 4; ++j) { accd[i][j] = 0.f; acca[i][j] = 0.f; }
        for (int q = 0; q < 64; ++q) {
            const float4 bv = *reinterpret_cast<const float4*>(&Ks[q * 64 + j0]);
            const float bb[4] = {bv.x, bv.y, bv.z, bv.w};
            float ad[4], aa[4];
#pragma unroll
            for (int i = 0; i < 4; ++i) {
                ad[i] = CPs[(i0 + i) * 64 + q];
                aa[i] = Ms[(i0 + i) * 64 + q];
            }
#pragma unroll
            for (int i = 0; i < 4; ++i)
#pragma unroll
                for (int j = 0; j < 4; ++j) {
                    accd[i][j] += ad[i] * bb[j];
                    acca[i][j] += aa[i] * bb[j];
                }
        }
#pragma unroll
        for (int i = 0; i < 4; ++i)
#pragma unroll
            for (int j = 0; j < 4; ++j) {
                Tds[(i0 + i) * 64 + j0 + j] = accd[i][j];
                Tas[(i0 + i) * 64 + j0 + j] = acca[i][j];
            }
    }
    __syncthreads();

    // T1 = 2*Td - Td*Ta ; E[e][(c0^16)+j] = q(c0+j) * T1[e][c0+j]
    {
        const int e0 = ty * 4, c0 = tx * 4;
        float acc[4][4];
#pragma unroll
        for (int i = 0; i < 4; ++i)
#pragma unroll
            for (int j = 0; j < 4; ++j) acc[i][j] = 0.f;
        for (int q = 0; q < 64; ++q) {
            const float4 bv = *reinterpret_cast<const float4*>(&Tas[q * 64 + c0]);
            const float bb[4] = {bv.x, bv.y, bv.z, bv.w};
            float a[4];
#pragma unroll
            for (int i = 0; i < 4; ++i) a[i] = Tds[(e0 + i) * 64 + q];
#pragma unroll
            for (int i = 0; i < 4; ++i)
#pragma unroll
                for (int j = 0; j < 4; ++j) acc[i][j] += a[i] * bb[j];
        }
        float qv[4];
#pragma unroll
        for (int j = 0; j < 4; ++j) qv[j] = qval(coeff, coeff_l, b, c0 + j);
#pragma unroll
        for (int i = 0; i < 4; ++i) {
            float4 o;
            o.x = qv[0] * (2.f * Tds[(e0 + i) * 64 + c0 + 0] - acc[i][0]);
            o.y = qv[1] * (2.f * Tds[(e0 + i) * 64 + c0 + 1] - acc[i][1]);
            o.z = qv[2] * (2.f * Tds[(e0 + i) * 64 + c0 + 2] - acc[i][2]);
            o.w = qv[3] * (2.f * Tds[(e0 + i) * 64 + c0 + 3] - acc[i][3]);
            *reinterpret_cast<float4*>(&Eout[b * 4096 + (e0 + i) * 64 + (c0 ^ 16)]) = o;
        }
    }
}

// SE_b = S * E_b   (512 x 64). grid (hc=8, b=8)
__global__ __launch_bounds__(256) void k_se(const float* l, const float* r,
                                            const float* ll, const float* rl,
                                            const float* Ein, float* SEout) {
    __shared__ float Es[4096];
    const int b = blockIdx.y, hc = blockIdx.x, t = threadIdx.x;
    for (int idx = t; idx < 4096; idx += 256) Es[idx] = Ein[b * 4096 + idx];
    __syncthreads();
    const int h = hc * 64 + (t >> 2);
    const int mg = (t & 3) * 16;
    float acc[16];
#pragma unroll
    for (int q = 0; q < 16; ++q) acc[q] = 0.f;
#pragma unroll 4
    for (int e = 0; e < 64; ++e) {
        const float s = Sval(l, r, ll, rl, h, e);
        const float* Er = Es + e * 64 + mg;
#pragma unroll
        for (int q = 0; q < 16; ++q) acc[q] += s * Er[q];
    }
    float* o = SEout + (size_t)b * (512 * 64) + h * 64 + mg;
#pragma unroll
    for (int q = 0; q < 4; ++q) {
        float4 v;
        v.x = acc[q * 4 + 0]; v.y = acc[q * 4 + 1];
        v.z = acc[q * 4 + 2]; v.w = acc[q * 4 + 3];
        *reinterpret_cast<float4*>(o + q * 4) = v;
    }
}

// out = x + ((x * SE_b) * S^T).  grid (row-tile=64, b=8), 64 rows per block.
__global__ __launch_bounds__(256) void k_mix(const float* x, const float* l, const float* r,
                                             const float* ll, const float* rl,
                                             const float* SE, float* out) {
    __shared__ float smem[12800];
    float* XsT = smem;
    float* SEs = smem + 4352;
    float* ZsT = smem;
    float* SsT = smem + 4352;

    const int b = blockIdx.y;
    const int r0 = blockIdx.x * 64;
    const int t = threadIdx.x;
    const int tx = t & 15, ty = t >> 4;
    const float* xb = x + (size_t)b * N_ * F_;
    float* outb = out + (size_t)b * N_ * F_;
    const float* SEb = SE + (size_t)b * (512 * 64);

    float acc[4][4];
#pragma unroll
    for (int i = 0; i < 4; ++i)
#pragma unroll
        for (int j = 0; j < 4; ++j) acc[i][j] = 0.f;

    const int lr = t >> 2;
    const int lc = (t & 3) * 16;

    // phase 1: Z[64][64] = X_tile[64][512] * SE[512][64]
    for (int kc = 0; kc < 8; ++kc) {
#pragma unroll
        for (int i = 0; i < 4; ++i) {
            const float4 v = *reinterpret_cast<const float4*>(
                xb + (size_t)(r0 + lr) * F_ + kc * 64 + lc + i * 4);
            XsT[(lc + i * 4 + 0) * 68 + lr] = v.x;
            XsT[(lc + i * 4 + 1) * 68 + lr] = v.y;
            XsT[(lc + i * 4 + 2) * 68 + lr] = v.z;
            XsT[(lc + i * 4 + 3) * 68 + lr] = v.w;
            const float4 w = *reinterpret_cast<const float4*>(
                SEb + (size_t)(kc * 64 + lr) * 64 + lc + i * 4);
            *reinterpret_cast<float4*>(&SEs[lr * 68 + lc + i * 4]) = w;
        }
        __syncthreads();
#pragma unroll 8
        for (int k = 0; k < 64; ++k) {
            const float4 a4 = *reinterpret_cast<const float4*>(&XsT[k * 68 + 4 * ty]);
            const float4 b4 = *reinterpret_cast<const float4*>(&SEs[k * 68 + 4 * tx]);
            const float av[4] = {a4.x, a4.y, a4.z, a4.w};
            const float bv[4] = {b4.x, b4.y, b4.z, b4.w};
#pragma unroll
            for (int i = 0; i < 4; ++i)
#pragma unroll
                for (int j = 0; j < 4; ++j) acc[i][j] += av[i] * bv[j];
        }
        __syncthreads();
    }

    // ZsT[m][r] = z[r][m]
#pragma unroll
    for (int j = 0; j < 4; ++j)
#pragma unroll
        for (int i = 0; i < 4; ++i)
            ZsT[(4 * tx + j) * 68 + 4 * ty + i] = acc[i][j];
    __syncthreads();

    // phase 2: out[64][512] = X + Z * S^T, h-chunks of 128
    for (int hc = 0; hc < 4; ++hc) {
        {
            const int gsel = t & 3;
            const int hl = t >> 2;
            const float* mat = (gsel == 0) ? l : (gsel == 1) ? r : (gsel == 2) ? ll : rl;
#pragma unroll
            for (int hh = 0; hh < 2; ++hh) {
                const int hloc = hl + hh * 64;
                const int h = hc * 128 + hloc;
#pragma unroll
                for (int q = 0; q < 4; ++q) {
                    const float4 v = *reinterpret_cast<const float4*>(mat + h * 16 + q * 4);
                    SsT[(gsel * 16 + q * 4 + 0) * 132 + hloc] = v.x;
                    SsT[(gsel * 16 + q * 4 + 1) * 132 + hloc] = v.y;
                    SsT[(gsel * 16 + q * 4 + 2) * 132 + hloc] = v.z;
                    SsT[(gsel * 16 + q * 4 + 3) * 132 + hloc] = v.w;
                }
            }
        }
        __syncthreads();

        float oacc[4][8];
#pragma unroll
        for (int i = 0; i < 4; ++i)
#pragma unroll
            for (int j = 0; j < 8; ++j) oacc[i][j] = 0.f;

#pragma unroll 8
        for (int e = 0; e < 64; ++e) {
            const float4 z4 = *reinterpret_cast<const float4*>(&ZsT[e * 68 + 4 * ty]);
            const float4 s0 = *reinterpret_cast<const float4*>(&SsT[e * 132 + 8 * tx]);
            const float4 s1 = *reinterpret_cast<const float4*>(&SsT[e * 132 + 8 * tx + 4]);
            const float zv[4] = {z4.x, z4.y, z4.z, z4.w};
            const float sv[8] = {s0.x, s0.y, s0.z, s0.w, s1.x, s1.y, s1.z, s1.w};
#pragma unroll
            for (int i = 0; i < 4; ++i)
#pragma unroll
                for (int j = 0; j < 8; ++j) oacc[i][j] += zv[i] * sv[j];
        }

#pragma unroll
        for (int i = 0; i < 4; ++i) {
            const size_t row = (size_t)(r0 + 4 * ty + i);
            const float* xr = xb + row * F_ + hc * 128 + 8 * tx;
            float* orow = outb + row * F_ + hc * 128 + 8 * tx;
            const float4 x0 = *reinterpret_cast<const float4*>(xr);
            const float4 x1 = *reinterpret_cast<const float4*>(xr + 4);
            float4 o0, o1;
            o0.x = x0.x + oacc[i][0]; o0.y = x0.y + oacc[i][1];
            o0.z = x0.z + oacc[i][2]; o0.w = x0.w + oacc[i][3];
            o1.x = x1.x + oacc[i][4]; o1.y = x1.y + oacc[i][5];
            o1.z = x1.z + oacc[i][6]; o1.w = x1.w + oacc[i][7];
            *reinterpret_cast<float4*>(orow) = o0;
            *reinterpret_cast<float4*>(orow + 4) = o1;
        }
        __syncthreads();
    }
}

extern "C" void kernel_launch(void* const* d_in, const int* in_sizes, int n_in,
                              void* d_out, int out_size, void* d_ws, size_t ws_size,
                              hipStream_t stream) {
    (void)in_sizes; (void)n_in; (void)out_size; (void)ws_size;
    const float* x       = (const float*)d_in[0];
    const float* coeff   = (const float*)d_in[1];
    const float* gate    = (const float*)d_in[2];
    const float* coeff_l = (const float*)d_in[3];
    const float* gate_l  = (const float*)d_in[4];
    const float* comm    = (const float*)d_in[5];
    const float* l       = (const float*)d_in[6];
    const float* r       = (const float*)d_in[7];
    const float* ll      = (const float*)d_in[8];
    const float* rl      = (const float*)d_in[9];

    float* wsf = (float*)d_ws;
    float* GS  = wsf;                        // 4096
    float* E   = wsf + 4096;                 // 8 * 4096
    float* SE  = wsf + 4096 + 8 * 4096;      // 8 * 512 * 64 = 262144
    float* Mws = SE + 262144;                // 8 * 4096
    float* CPws = Mws + 8 * 4096;            // 8 * 4096
    float* Kws  = CPws + 8 * 4096;           // 8 * 4096
    float* out = (float*)d_out;

    k_gram<<<dim3(64), dim3(256), 0, stream>>>(l, r, ll, rl, GS);
    k_build_pre<<<dim3(8), dim3(256), 0, stream>>>(coeff, gate, coeff_l, gate_l, comm, GS,
                                                   Mws, CPws);
    k_inv<<<dim3(8), dim3(64), 0, stream>>>(Mws, Kws);
    k_build_post<<<dim3(8), dim3(256), 0, stream>>>(coeff, coeff_l, Mws, CPws, Kws, E);
    k_se<<<dim3(8, 8), dim3(256), 0, stream>>>(l, r, ll, rl, E, SE);
    k_mix<<<dim3(64, 8), dim3(256), 0, stream>>>(x, l, r, ll, rl, SE, out);
}